// Round 11
// baseline (296.194 us; speedup 1.0000x reference)
//
#include <hip/hip_runtime.h>
#include <hip/hip_fp16.h>

#define NC 16384        // num classes == batch
#define FD 128          // feature dim
#define LAMBDA 0.005f
#define SLOTCAP 64      // max samples tracked per class (Poisson(1): max ~10)
#define GRID 512

__device__ __forceinline__ float wave_sum(float v) {
#pragma unroll
  for (int m = 32; m > 0; m >>= 1) v += __shfl_xor(v, m, 64);
  return v;
}

// manual grid barrier: arrive + spin on device-scope counter (one slot per use)
__device__ __forceinline__ void grid_sync(int* sync, int slot) {
  __syncthreads();
  if (threadIdx.x == 0) {
    int* p = &sync[slot * 16];
    __threadfence();  // release: make prior writes visible device-wide
    __hip_atomic_fetch_add(p, 1, __ATOMIC_ACQ_REL, __HIP_MEMORY_SCOPE_AGENT);
    while (__hip_atomic_load(p, __ATOMIC_ACQUIRE, __HIP_MEMORY_SCOPE_AGENT) < GRID)
      __builtin_amdgcn_s_sleep(2);
    __threadfence();  // acquire: invalidate caches before consuming others' data
  }
  __syncthreads();
}

// --- pre: zero cnt + scal + sync counters (one tiny launch) -------------------
__global__ __launch_bounds__(256) void pre_kernel(int4* __restrict__ cnt4,
                                                  float* __restrict__ scal,
                                                  int* __restrict__ sync) {
  int g = blockIdx.x * 256 + threadIdx.x;
  cnt4[g] = make_int4(0, 0, 0, 0);  // 16 blocks x 256 x int4 = NC ints
  if (g < 16) scal[g] = 0.f;
  if (g < 128) sync[g] = 0;
}

// --- persistent kernel: scatter | center+diag | gram_z||gram_c | reduce | loss
__global__ __launch_bounds__(256, 2) void persist_kernel(
    const float* __restrict__ z, const int* __restrict__ labels,
    float* __restrict__ out, int* __restrict__ cnt, int* __restrict__ slot,
    float* __restrict__ cn, float2* __restrict__ dpart,
    __half2* __restrict__ pz, __half2* __restrict__ pc,
    float2* __restrict__ rz, float2* __restrict__ rc,
    float* __restrict__ scal, int* __restrict__ sync) {
  __shared__ float tile[64 * FD];  // 32 KB; aliased as red[] in non-gram phases
  int t = threadIdx.x, wave = t >> 6, lane = t & 63;
  int b = blockIdx.x;

  // ---- B: scatter labels -> slot lists (blocks 0..63) -----------------------
  if (b < 64) {
    int i = b * 256 + t;
    int lab = labels[i];
    int p = atomicAdd(&cnt[lab], 1);
    if (p < SLOTCAP) slot[lab * SLOTCAP + p] = i;
  }
  grid_sync(sync, 0);

  // ---- C: center + diag: 32 classes/block, 8/wave, prefetched for MLP -------
  {
    int cb = b * 32 + wave * 8;
    int n[8], i0[8];
#pragma unroll
    for (int j = 0; j < 8; ++j) {
      int nn = cnt[cb + j];
      n[j] = nn > SLOTCAP ? SLOTCAP : nn;
    }
#pragma unroll
    for (int j = 0; j < 8; ++j)
      i0[j] = n[j] > 0 ? slot[(cb + j) * SLOTCAP] : 0;
    float s1 = 0.f, s2 = 0.f;
#pragma unroll
    for (int j = 0; j < 8; ++j) {
      int c = cb + j;
      float2 s = make_float2(0.f, 0.f);
      if (n[j] > 0) {
        float2 v = *(const float2*)&z[(size_t)i0[j] * FD + lane * 2];
        s.x = v.x; s.y = v.y;
        for (int k = 1; k < n[j]; ++k) {
          int i = slot[c * SLOTCAP + k];
          float2 v2 = *(const float2*)&z[(size_t)i * FD + lane * 2];
          s.x += v2.x; s.y += v2.y;
        }
        float inv = 1.0f / (float)n[j];
        s.x *= inv; s.y *= inv;
      }
      float sc = wave_sum(s.x * s.x + s.y * s.y);
      float ic = 1.0f / fmaxf(sqrtf(sc), 1e-12f);
      s.x *= ic; s.y *= ic;
      *(float2*)&cn[(size_t)c * FD + lane * 2] = s;
      float2 a = *(const float2*)&z[(size_t)c * FD + lane * 2];
      float na = wave_sum(a.x * a.x + a.y * a.y);
      float dd = wave_sum(a.x * s.x + a.y * s.y);
      float d = dd * (1.0f / fmaxf(sqrtf(na), 1e-12f));
      s1 += d; s2 += d * d;
    }
    float* red = tile;
    if (lane == 0) { red[wave * 2] = s1; red[wave * 2 + 1] = s2; }
    __syncthreads();
    if (t == 0)
      dpart[b] = make_float2(red[0] + red[2] + red[4] + red[6],
                             red[1] + red[3] + red[5] + red[7]);
  }
  grid_sync(sync, 1);

  // ---- D: gram partials: b<256 -> z chunk b; b>=256 -> cn chunk b-256 -------
  {
    int m = b >> 8;
    int chunk = b & 255;
    const float* A = m ? cn : z;
    const float4* t4 = (const float4*)tile;
    {  // stage 64x128 fp32, coalesced float4
      const float4* src = (const float4*)&A[(size_t)chunk * 64 * FD];
      float4* dst = (float4*)tile;
#pragma unroll
      for (int k = 0; k < 8; ++k) dst[k * 256 + t] = src[k * 256 + t];
    }
    __syncthreads();
    if (m == 0) {  // normalize z rows in LDS (16 rows per wave)
      float2* t2 = (float2*)tile;
#pragma unroll
      for (int j = 0; j < 16; ++j) {
        int row = wave * 16 + j;
        float2 v = t2[row * 64 + lane];
        float ss = wave_sum(v.x * v.x + v.y * v.y);
        float scn = 1.0f / fmaxf(sqrtf(ss), 1e-12f);
        v.x *= scn; v.y *= scn;
        t2[row * 64 + lane] = v;
      }
      __syncthreads();
    }
    int tx = t & 15, ty = t >> 4;
    float4 acc[8][2];
#pragma unroll
    for (int i = 0; i < 8; ++i) {
      acc[i][0] = make_float4(0.f, 0.f, 0.f, 0.f);
      acc[i][1] = make_float4(0.f, 0.f, 0.f, 0.f);
    }
    float4 a0 = t4[ty * 2], a1 = t4[ty * 2 + 1];
    float4 b0 = t4[tx * 2], b1 = t4[tx * 2 + 1];
    for (int r = 0; r < 64; ++r) {
      int rn = (r + 1) & 63;
      float4 na0 = t4[rn * 32 + ty * 2];
      float4 na1 = t4[rn * 32 + ty * 2 + 1];
      float4 nb0 = t4[rn * 32 + tx * 2];
      float4 nb1 = t4[rn * 32 + tx * 2 + 1];
      float av[8] = {a0.x, a0.y, a0.z, a0.w, a1.x, a1.y, a1.z, a1.w};
#pragma unroll
      for (int i = 0; i < 8; ++i) {
        float aa = av[i];
        acc[i][0].x += aa * b0.x; acc[i][0].y += aa * b0.y;
        acc[i][0].z += aa * b0.z; acc[i][0].w += aa * b0.w;
        acc[i][1].x += aa * b1.x; acc[i][1].y += aa * b1.y;
        acc[i][1].z += aa * b1.z; acc[i][1].w += aa * b1.w;
      }
      a0 = na0; a1 = na1; b0 = nb0; b1 = nb1;
    }
    __half2* P = (m ? pc : pz) + (size_t)chunk * 8192;
    int d0 = ty * 8, e0h = tx * 4;  // half2 column
#pragma unroll
    for (int i = 0; i < 8; ++i) {
      __half2 h0 = __floats2half2_rn(acc[i][0].x, acc[i][0].y);
      __half2 h1 = __floats2half2_rn(acc[i][0].z, acc[i][0].w);
      __half2 h2 = __floats2half2_rn(acc[i][1].x, acc[i][1].y);
      __half2 h3 = __floats2half2_rn(acc[i][1].z, acc[i][1].w);
      uint4 u = make_uint4(*(unsigned*)&h0, *(unsigned*)&h1,
                           *(unsigned*)&h2, *(unsigned*)&h3);
      *(uint4*)&P[(d0 + i) * 64 + e0h] = u;
    }
  }
  grid_sync(sync, 2);

  // ---- E1: reduce 256 chunks -> 16 groups, fully coalesced ------------------
  {
    int g = b >> 5, s = b & 31;  // 16 groups x 32 slices (256 half2 each)
    float2 az = make_float2(0.f, 0.f), ac = make_float2(0.f, 0.f);
#pragma unroll
    for (int k = 0; k < 16; ++k) {
      size_t idx = (size_t)(g * 16 + k) * 8192 + s * 256 + t;
      float2 fz = __half22float2(pz[idx]);
      float2 fc = __half22float2(pc[idx]);
      az.x += fz.x; az.y += fz.y;
      ac.x += fc.x; ac.y += fc.y;
    }
    rz[(size_t)g * 8192 + s * 256 + t] = az;
    rc[(size_t)g * 8192 + s * 256 + t] = ac;
  }
  grid_sync(sync, 3);

  // ---- E2: Frobenius + loss (blocks 0..31; ticket-last composes) ------------
  if (b < 32) {
    int e = b * 256 + t;
    float2 tz = make_float2(0.f, 0.f), tc = make_float2(0.f, 0.f);
#pragma unroll
    for (int g = 0; g < 16; ++g) {
      float2 fz = rz[(size_t)g * 8192 + e];
      float2 fc = rc[(size_t)g * 8192 + e];
      tz.x += fz.x; tz.y += fz.y;
      tc.x += fc.x; tc.y += fc.y;
    }
    float Sw = wave_sum(tz.x * tc.x + tz.y * tc.y);
    float* red = tile;
    int* ired = (int*)tile;
    if (lane == 0) red[wave] = Sw;
    __syncthreads();
    if (t == 0) {
      float S = red[0] + red[1] + red[2] + red[3];
      unsafeAtomicAdd(&scal[2], S);
      __threadfence();
      ired[8] = atomicAdd(&sync[5 * 16], 1);  // ticket
    }
    __syncthreads();
    if (ired[8] == 31 && wave == 0) {
      float a1 = 0.f, a2 = 0.f;
#pragma unroll
      for (int k = 0; k < 8; ++k) {
        float2 d = dpart[k * 64 + lane];
        a1 += d.x; a2 += d.y;
      }
      a1 = wave_sum(a1);
      a2 = wave_sum(a2);
      if (lane == 0) {
        float SS = atomicAdd(&scal[2], 0.0f);  // coherent read of total
        double S1 = a1, S2 = a2, Sall = SS;
        double B = (double)NC;
        double inv_loss = S2 / (B * B) - 2.0 * S1 / B + (double)NC;
        double red_loss = (Sall - S2) / (B * B);
        out[0] = (float)(inv_loss + (double)LAMBDA * red_loss);
      }
    }
  }
}

extern "C" void kernel_launch(void* const* d_in, const int* in_sizes, int n_in,
                              void* d_out, int out_size, void* d_ws, size_t ws_size,
                              hipStream_t stream) {
  const float* z = (const float*)d_in[0];
  const int* labels = (const int*)d_in[1];
  float* out = (float*)d_out;
  float* ws = (float*)d_ws;

  // ws layout (floats):
  // [cn NC*FD][pz 256*8192 h2][pc 256*8192 h2][rz 16*8192 f2][rc 16*8192 f2]
  // [dpart 512 f2][scal 16][sync 128 int][cnt NC int][slot NC*SLOTCAP int]
  float* cn = ws;
  __half2* pz = (__half2*)(cn + (size_t)NC * FD);
  __half2* pc = pz + (size_t)256 * 8192;
  float2* rz = (float2*)(pc + (size_t)256 * 8192);
  float2* rc = rz + (size_t)16 * 8192;
  float2* dpart = rc + (size_t)16 * 8192;
  float* scal = (float*)(dpart + 512);
  int* syncp = (int*)(scal + 16);
  int* cnt = syncp + 128;
  int* slot = cnt + NC;

  pre_kernel<<<16, 256, 0, stream>>>((int4*)cnt, scal, syncp);
  persist_kernel<<<GRID, 256, 0, stream>>>(z, labels, out, cnt, slot, cn, dpart,
                                           pz, pc, rz, rc, scal, syncp);
}

// Round 12
// 68.987 us; speedup vs baseline: 4.2935x; 4.2935x over previous
//
#include <hip/hip_runtime.h>
#include <hip/hip_fp16.h>

#define NC 16384        // num classes == batch
#define FD 128          // feature dim
#define LAMBDA 0.005f
#define SLOTCAP 64      // max samples tracked per class (Poisson(1): max ~10)
#define NCH 256         // 64-row K-chunks per matrix

__device__ __forceinline__ float wave_sum(float v) {
#pragma unroll
  for (int m = 32; m > 0; m >>= 1) v += __shfl_xor(v, m, 64);
  return v;
}

// 64-row chunk gram: G_partial = T^T T (128x128) -> fp16 partial store.
// 8x8 patch per thread, one-row register prefetch (R7's measured structure).
__device__ __forceinline__ void gram_chunk(const float* __restrict__ A, int chunk,
                                           int normalize, __half2* __restrict__ P,
                                           float* tile, int t, int wave, int lane) {
  const float4* t4 = (const float4*)tile;
  {  // stage 64x128 fp32, coalesced float4
    const float4* src = (const float4*)&A[(size_t)chunk * 64 * FD];
    float4* dst = (float4*)tile;
#pragma unroll
    for (int k = 0; k < 8; ++k) dst[k * 256 + t] = src[k * 256 + t];
  }
  __syncthreads();
  if (normalize) {  // L2-normalize rows in LDS (16 rows per wave)
    float2* t2 = (float2*)tile;
#pragma unroll
    for (int j = 0; j < 16; ++j) {
      int row = wave * 16 + j;
      float2 v = t2[row * 64 + lane];
      float ss = wave_sum(v.x * v.x + v.y * v.y);
      float sc = 1.0f / fmaxf(sqrtf(ss), 1e-12f);
      v.x *= sc; v.y *= sc;
      t2[row * 64 + lane] = v;
    }
    __syncthreads();
  }
  int tx = t & 15, ty = t >> 4;
  float4 acc[8][2];
#pragma unroll
  for (int i = 0; i < 8; ++i) {
    acc[i][0] = make_float4(0.f, 0.f, 0.f, 0.f);
    acc[i][1] = make_float4(0.f, 0.f, 0.f, 0.f);
  }
  float4 a0 = t4[ty * 2], a1 = t4[ty * 2 + 1];
  float4 b0 = t4[tx * 2], b1 = t4[tx * 2 + 1];
  for (int r = 0; r < 64; ++r) {
    int rn = (r + 1) & 63;
    float4 na0 = t4[rn * 32 + ty * 2];
    float4 na1 = t4[rn * 32 + ty * 2 + 1];
    float4 nb0 = t4[rn * 32 + tx * 2];
    float4 nb1 = t4[rn * 32 + tx * 2 + 1];
    float av[8] = {a0.x, a0.y, a0.z, a0.w, a1.x, a1.y, a1.z, a1.w};
#pragma unroll
    for (int i = 0; i < 8; ++i) {
      float aa = av[i];
      acc[i][0].x += aa * b0.x; acc[i][0].y += aa * b0.y;
      acc[i][0].z += aa * b0.z; acc[i][0].w += aa * b0.w;
      acc[i][1].x += aa * b1.x; acc[i][1].y += aa * b1.y;
      acc[i][1].z += aa * b1.z; acc[i][1].w += aa * b1.w;
    }
    a0 = na0; a1 = na1; b0 = nb0; b1 = nb1;
  }
  __half2* Pc = P + (size_t)chunk * 8192;
  int d0 = ty * 8;
#pragma unroll
  for (int i = 0; i < 8; ++i) {
    __half2 h0 = __floats2half2_rn(acc[i][0].x, acc[i][0].y);
    __half2 h1 = __floats2half2_rn(acc[i][0].z, acc[i][0].w);
    __half2 h2 = __floats2half2_rn(acc[i][1].x, acc[i][1].y);
    __half2 h3 = __floats2half2_rn(acc[i][1].z, acc[i][1].w);
    uint4 u = make_uint4(*(unsigned*)&h0, *(unsigned*)&h1,
                         *(unsigned*)&h2, *(unsigned*)&h3);
    *(uint4*)&Pc[(d0 + i) * 64 + tx * 4] = u;
  }
}

// --- 1. zero cnt + scal --------------------------------------------------------
__global__ __launch_bounds__(256) void zero_kernel(int4* __restrict__ cnt4,
                                                   float* __restrict__ scal) {
  cnt4[blockIdx.x * 256 + threadIdx.x] = make_int4(0, 0, 0, 0);
  if (blockIdx.x == 0 && threadIdx.x < 16) scal[threadIdx.x] = 0.f;
}

// --- 2. scatter: slot[lab][k] = sample index ------------------------------------
__global__ __launch_bounds__(256) void scatter_kernel(
    const int* __restrict__ labels, int* __restrict__ cnt, int* __restrict__ slot) {
  int i = blockIdx.x * 256 + threadIdx.x;
  int lab = labels[i];
  int p = atomicAdd(&cnt[lab], 1);
  if (p < SLOTCAP) slot[(size_t)lab * SLOTCAP + p] = i;
}

// --- 3. hetero: blocks [0,NCH) gram_z; [NCH, NCH+4096) center+diag --------------
__global__ __launch_bounds__(256) void phase3_kernel(
    const float* __restrict__ z, const int* __restrict__ cnt,
    const int* __restrict__ slot, float* __restrict__ cn,
    float2* __restrict__ dpart, __half2* __restrict__ pz) {
  __shared__ float tile[64 * FD];  // 32 KB (gram); aliased as red[] by center
  int t = threadIdx.x, wave = t >> 6, lane = t & 63;
  int b = blockIdx.x;

  if (b < NCH) {
    gram_chunk(z, b, 1, pz, tile, t, wave, lane);
    return;
  }
  // center + diag: one class per wave (R7's measured structure)
  int c = (b - NCH) * 4 + wave;
  int n = cnt[c];
  if (n > SLOTCAP) n = SLOTCAP;
  float2 s = make_float2(0.f, 0.f);
  for (int k = 0; k < n; ++k) {
    int i = slot[(size_t)c * SLOTCAP + k];
    float2 v = *(const float2*)&z[(size_t)i * FD + lane * 2];
    s.x += v.x; s.y += v.y;
  }
  float inv = n > 0 ? 1.0f / (float)n : 0.0f;
  s.x *= inv; s.y *= inv;
  float sc = wave_sum(s.x * s.x + s.y * s.y);
  float ic = 1.0f / fmaxf(sqrtf(sc), 1e-12f);
  s.x *= ic; s.y *= ic;
  *(float2*)&cn[(size_t)c * FD + lane * 2] = s;

  float2 a = *(const float2*)&z[(size_t)c * FD + lane * 2];
  float na = wave_sum(a.x * a.x + a.y * a.y);
  float dd = wave_sum(a.x * s.x + a.y * s.y);
  float d = dd * (1.0f / fmaxf(sqrtf(na), 1e-12f));
  float* red = tile;
  if (lane == 0) { red[wave * 2] = d; red[wave * 2 + 1] = d * d; }
  __syncthreads();
  if (t == 0) {
    dpart[b - NCH] = make_float2(red[0] + red[2] + red[4] + red[6],
                                 red[1] + red[3] + red[5] + red[7]);
  }
}

// --- 4. gram_c: 256 chunk blocks over cn (already unit rows) --------------------
__global__ __launch_bounds__(256) void gramc_kernel(
    const float* __restrict__ cn, __half2* __restrict__ pc) {
  __shared__ float tile[64 * FD];
  int t = threadIdx.x;
  gram_chunk(cn, blockIdx.x, 0, pc, tile, t, t >> 6, t & 63);
}

// --- 5. reduce fp16 partials + Frobenius + final loss (last-block ticket) -------
__global__ __launch_bounds__(256) void reduce_final_kernel(
    const __half2* __restrict__ pz, const __half2* __restrict__ pc,
    const float2* __restrict__ dpart, float* __restrict__ scal,
    float* __restrict__ out) {
  __shared__ float2 lz[4][64], lc[4][64];
  int t = threadIdx.x, wave = t >> 6, lane = t & 63;
  int e2 = blockIdx.x * 64 + lane;  // half2 index in [0, 8192)
  float2 sz = make_float2(0.f, 0.f), sc = make_float2(0.f, 0.f);
  for (int k = 0; k < NCH / 4; ++k) {
    size_t c = (size_t)(wave * (NCH / 4) + k) * 8192 + e2;
    float2 fz = __half22float2(pz[c]);
    float2 fc = __half22float2(pc[c]);
    sz.x += fz.x; sz.y += fz.y;
    sc.x += fc.x; sc.y += fc.y;
  }
  lz[wave][lane] = sz;
  lc[wave][lane] = sc;
  __syncthreads();
  if (wave == 0) {
    float2 tz = make_float2(0.f, 0.f), tc = make_float2(0.f, 0.f);
#pragma unroll
    for (int w = 0; w < 4; ++w) {
      tz.x += lz[w][lane].x; tz.y += lz[w][lane].y;
      tc.x += lc[w][lane].x; tc.y += lc[w][lane].y;
    }
    float S = wave_sum(tz.x * tc.x + tz.y * tc.y);
    int* ticket_p = (int*)&scal[8];
    int ticket = 0;
    if (lane == 0) {
      unsafeAtomicAdd(&scal[2], S);
      __threadfence();
      ticket = atomicAdd(ticket_p, 1);
    }
    ticket = __shfl(ticket, 0, 64);
    if (ticket == 127) {  // last block: compose the loss
      float a1 = 0.f, a2 = 0.f;
      for (int k = lane; k < 4096; k += 64) {
        float2 d = dpart[k];
        a1 += d.x; a2 += d.y;
      }
      a1 = wave_sum(a1);
      a2 = wave_sum(a2);
      if (lane == 0) {
        float SS = atomicAdd(&scal[2], 0.0f);  // coherent read of total
        double S1 = a1, S2 = a2, Sall = SS;
        double B = (double)NC;
        double inv_loss = S2 / (B * B) - 2.0 * S1 / B + (double)NC;
        double red_loss = (Sall - S2) / (B * B);
        out[0] = (float)(inv_loss + (double)LAMBDA * red_loss);
      }
    }
  }
}

extern "C" void kernel_launch(void* const* d_in, const int* in_sizes, int n_in,
                              void* d_out, int out_size, void* d_ws, size_t ws_size,
                              hipStream_t stream) {
  const float* z = (const float*)d_in[0];
  const int* labels = (const int*)d_in[1];
  float* out = (float*)d_out;
  float* ws = (float*)d_ws;

  // ws layout (floats):
  // [cn NC*FD][pz NCH*8192 h2][pc NCH*8192 h2][dpart 4096 f2][scal 16]
  // [cnt NC int][slot NC*SLOTCAP int]
  float* cn = ws;
  __half2* pz = (__half2*)(cn + (size_t)NC * FD);
  __half2* pc = pz + (size_t)NCH * 8192;
  float2* dpart = (float2*)(pc + (size_t)NCH * 8192);
  float* scal = (float*)(dpart + 4096);
  int* cnt = (int*)(scal + 16);
  int* slot = cnt + NC;

  zero_kernel<<<NC / 1024, 256, 0, stream>>>((int4*)cnt, scal);
  scatter_kernel<<<NC / 256, 256, 0, stream>>>(labels, cnt, slot);
  phase3_kernel<<<NCH + NC / 4, 256, 0, stream>>>(z, cnt, slot, cn, dpart, pz);
  gramc_kernel<<<NCH, 256, 0, stream>>>(cn, pc);
  reduce_final_kernel<<<128, 256, 0, stream>>>(pz, pc, dpart, scal, out);
}

// Round 13
// 51.395 us; speedup vs baseline: 5.7631x; 1.3423x over previous
//
#include <hip/hip_runtime.h>
#include <hip/hip_fp16.h>

#define NC 16384        // num classes == batch
#define FD 128          // feature dim
#define LAMBDA 0.005f
#define SLOTCAP 64      // max samples tracked per class (Poisson(1): max ~10)
#define NCH 256         // 64-row K-chunks per matrix

__device__ __forceinline__ float wave_sum(float v) {
#pragma unroll
  for (int m = 32; m > 0; m >>= 1) v += __shfl_xor(v, m, 64);
  return v;
}

// --- 1. zero cnt + scal (R7 verbatim) -----------------------------------------
__global__ __launch_bounds__(256) void zero_kernel(int4* __restrict__ cnt4,
                                                   float* __restrict__ scal) {
  cnt4[blockIdx.x * 256 + threadIdx.x] = make_int4(0, 0, 0, 0);
  if (blockIdx.x == 0 && threadIdx.x < 16) scal[threadIdx.x] = 0.f;
}

// --- 2. scatter: slot[lab][k] = sample index (R7 verbatim) ----------------------
__global__ __launch_bounds__(256) void scatter_kernel(
    const int* __restrict__ labels, int* __restrict__ cnt, int* __restrict__ slot) {
  int i = blockIdx.x * 256 + threadIdx.x;
  int lab = labels[i];
  int p = atomicAdd(&cnt[lab], 1);
  if (p < SLOTCAP) slot[(size_t)lab * SLOTCAP + p] = i;
}

// --- 3. centers + diag: one wave per class (R7 verbatim) ------------------------
__global__ __launch_bounds__(256) void center_kernel(
    const float* __restrict__ z, const int* __restrict__ cnt,
    const int* __restrict__ slot, float* __restrict__ cn,
    float2* __restrict__ dpart) {
  __shared__ float red[8];
  int t = threadIdx.x, wave = t >> 6, lane = t & 63;
  int c = blockIdx.x * 4 + wave;

  int n = cnt[c];
  if (n > SLOTCAP) n = SLOTCAP;
  float2 s = make_float2(0.f, 0.f);
  for (int k = 0; k < n; ++k) {
    int i = slot[(size_t)c * SLOTCAP + k];
    float2 v = *(const float2*)&z[(size_t)i * FD + lane * 2];
    s.x += v.x; s.y += v.y;
  }
  float inv = n > 0 ? 1.0f / (float)n : 0.0f;
  s.x *= inv; s.y *= inv;
  float sc = wave_sum(s.x * s.x + s.y * s.y);
  float ic = 1.0f / fmaxf(sqrtf(sc), 1e-12f);
  s.x *= ic; s.y *= ic;
  *(float2*)&cn[(size_t)c * FD + lane * 2] = s;

  // diag: d_c = (z_c / ||z_c||) . cn_c
  float2 a = *(const float2*)&z[(size_t)c * FD + lane * 2];
  float na = wave_sum(a.x * a.x + a.y * a.y);
  float dd = wave_sum(a.x * s.x + a.y * s.y);
  float d = dd * (1.0f / fmaxf(sqrtf(na), 1e-12f));
  if (lane == 0) { red[wave * 2] = d; red[wave * 2 + 1] = d * d; }
  __syncthreads();
  if (t == 0) {
    dpart[blockIdx.x] = make_float2(red[0] + red[2] + red[4] + red[6],
                                    red[1] + red[3] + red[5] + red[7]);
  }
}

// --- 4. gram partials (R7 structure; fp16 store) --------------------------------
// block b: matrix m=b&1 (0->z normalized, 1->cn), 64-row chunk b>>1.
__global__ __launch_bounds__(256) void gram_kernel(
    const float* __restrict__ z, const float* __restrict__ cn,
    __half2* __restrict__ pz, __half2* __restrict__ pc) {
  __shared__ float tile[64 * FD];  // 32 KB
  int t = threadIdx.x, wave = t >> 6, lane = t & 63;
  int b = blockIdx.x;
  int m = b & 1;
  int chunk = b >> 1;
  const float* A = m ? cn : z;
  const float4* t4 = (const float4*)tile;

  {  // stage 64x128 fp32, coalesced float4
    const float4* src = (const float4*)&A[(size_t)chunk * 64 * FD];
    float4* dst = (float4*)tile;
#pragma unroll
    for (int k = 0; k < 8; ++k) dst[k * 256 + t] = src[k * 256 + t];
  }
  __syncthreads();
  if (m == 0) {  // normalize z rows in LDS (16 rows per wave)
    float2* t2 = (float2*)tile;
#pragma unroll
    for (int j = 0; j < 16; ++j) {
      int row = wave * 16 + j;
      float2 v = t2[row * 64 + lane];
      float ss = wave_sum(v.x * v.x + v.y * v.y);
      float sc = 1.0f / fmaxf(sqrtf(ss), 1e-12f);
      v.x *= sc; v.y *= sc;
      t2[row * 64 + lane] = v;
    }
    __syncthreads();
  }

  int tx = t & 15, ty = t >> 4;
  float4 acc[8][2];
#pragma unroll
  for (int i = 0; i < 8; ++i) {
    acc[i][0] = make_float4(0.f, 0.f, 0.f, 0.f);
    acc[i][1] = make_float4(0.f, 0.f, 0.f, 0.f);
  }
  float4 a0 = t4[ty * 2], a1 = t4[ty * 2 + 1];
  float4 b0 = t4[tx * 2], b1 = t4[tx * 2 + 1];
  for (int r = 0; r < 64; ++r) {
    int rn = (r + 1) & 63;
    float4 na0 = t4[rn * 32 + ty * 2];
    float4 na1 = t4[rn * 32 + ty * 2 + 1];
    float4 nb0 = t4[rn * 32 + tx * 2];
    float4 nb1 = t4[rn * 32 + tx * 2 + 1];
    float av[8] = {a0.x, a0.y, a0.z, a0.w, a1.x, a1.y, a1.z, a1.w};
#pragma unroll
    for (int i = 0; i < 8; ++i) {
      float aa = av[i];
      acc[i][0].x += aa * b0.x; acc[i][0].y += aa * b0.y;
      acc[i][0].z += aa * b0.z; acc[i][0].w += aa * b0.w;
      acc[i][1].x += aa * b1.x; acc[i][1].y += aa * b1.y;
      acc[i][1].z += aa * b1.z; acc[i][1].w += aa * b1.w;
    }
    a0 = na0; a1 = na1; b0 = nb0; b1 = nb1;
  }

  __half2* P = (m ? pc : pz) + (size_t)chunk * 8192;
  int d0 = ty * 8;
#pragma unroll
  for (int i = 0; i < 8; ++i) {
    __half2 h0 = __floats2half2_rn(acc[i][0].x, acc[i][0].y);
    __half2 h1 = __floats2half2_rn(acc[i][0].z, acc[i][0].w);
    __half2 h2 = __floats2half2_rn(acc[i][1].x, acc[i][1].y);
    __half2 h3 = __floats2half2_rn(acc[i][1].z, acc[i][1].w);
    uint4 u = make_uint4(*(unsigned*)&h0, *(unsigned*)&h1,
                         *(unsigned*)&h2, *(unsigned*)&h3);
    *(uint4*)&P[(d0 + i) * 64 + tx * 4] = u;
  }
}

// --- 5. reduce fp16 partials + Frobenius + loss; last-block sum is FULL-BLOCK ---
__global__ __launch_bounds__(256) void reduce_final_kernel(
    const __half2* __restrict__ pz, const __half2* __restrict__ pc,
    const float2* __restrict__ dpart, float* __restrict__ scal,
    int* __restrict__ ticket_p, float* __restrict__ out) {
  __shared__ float2 lz[4][64], lc[4][64];
  __shared__ float rr[2][4];
  __shared__ int tk;
  int t = threadIdx.x, wave = t >> 6, lane = t & 63;
  int e2 = blockIdx.x * 64 + lane;  // half2 index in [0, 8192)
  float2 sz = make_float2(0.f, 0.f), sc = make_float2(0.f, 0.f);
  for (int k = 0; k < NCH / 4; ++k) {
    size_t c = (size_t)(wave * (NCH / 4) + k) * 8192 + e2;
    float2 fz = __half22float2(pz[c]);
    float2 fc = __half22float2(pc[c]);
    sz.x += fz.x; sz.y += fz.y;
    sc.x += fc.x; sc.y += fc.y;
  }
  lz[wave][lane] = sz;
  lc[wave][lane] = sc;
  __syncthreads();
  if (wave == 0) {
    float2 tz = make_float2(0.f, 0.f), tc = make_float2(0.f, 0.f);
#pragma unroll
    for (int w = 0; w < 4; ++w) {
      tz.x += lz[w][lane].x; tz.y += lz[w][lane].y;
      tc.x += lc[w][lane].x; tc.y += lc[w][lane].y;
    }
    float S = wave_sum(tz.x * tc.x + tz.y * tc.y);
    if (lane == 0) {
      unsafeAtomicAdd(&scal[2], S);
      __threadfence();
      tk = atomicAdd(ticket_p, 1);
    }
  }
  __syncthreads();
  if (tk == 127) {  // last block: compose loss with ALL 256 threads coalesced
    float a1 = 0.f, a2 = 0.f;
#pragma unroll
    for (int k = 0; k < 16; ++k) {
      float2 d = dpart[k * 256 + t];
      a1 += d.x; a2 += d.y;
    }
    a1 = wave_sum(a1);
    a2 = wave_sum(a2);
    if (lane == 0) { rr[0][wave] = a1; rr[1][wave] = a2; }
    __syncthreads();
    if (t == 0) {
      float SS = atomicAdd(&scal[2], 0.0f);  // coherent read of the full total
      double S1 = (double)rr[0][0] + rr[0][1] + rr[0][2] + rr[0][3];
      double S2 = (double)rr[1][0] + rr[1][1] + rr[1][2] + rr[1][3];
      double Sall = SS;
      double B = (double)NC;
      double inv_loss = S2 / (B * B) - 2.0 * S1 / B + (double)NC;
      double red_loss = (Sall - S2) / (B * B);
      out[0] = (float)(inv_loss + (double)LAMBDA * red_loss);
    }
  }
}

extern "C" void kernel_launch(void* const* d_in, const int* in_sizes, int n_in,
                              void* d_out, int out_size, void* d_ws, size_t ws_size,
                              hipStream_t stream) {
  const float* z = (const float*)d_in[0];
  const int* labels = (const int*)d_in[1];
  float* out = (float*)d_out;
  float* ws = (float*)d_ws;

  // ws layout (floats):
  // [cn NC*FD][pz NCH*8192 h2][pc NCH*8192 h2][dpart 4096 f2][scal 16]
  // [cnt NC int][slot NC*SLOTCAP int]
  float* cn = ws;
  __half2* pz = (__half2*)(cn + (size_t)NC * FD);
  __half2* pc = pz + (size_t)NCH * 8192;
  float2* dpart = (float2*)(pc + (size_t)NCH * 8192);
  float* scal = (float*)(dpart + 4096);
  int* cnt = (int*)(scal + 16);
  int* slot = cnt + NC;
  int* ticket = (int*)&scal[8];

  zero_kernel<<<NC / 1024, 256, 0, stream>>>((int4*)cnt, scal);
  scatter_kernel<<<NC / 256, 256, 0, stream>>>(labels, cnt, slot);
  center_kernel<<<NC / 4, 256, 0, stream>>>(z, cnt, slot, cn, dpart);
  gram_kernel<<<2 * NCH, 256, 0, stream>>>(z, cn, pz, pc);
  reduce_final_kernel<<<128, 256, 0, stream>>>(pz, pc, dpart, scal, ticket, out);
}

// Round 14
// 46.639 us; speedup vs baseline: 6.3508x; 1.1020x over previous
//
#include <hip/hip_runtime.h>
#include <hip/hip_fp16.h>

#define NC 16384        // num classes == batch
#define FD 128          // feature dim
#define LAMBDA 0.005f
#define SLOTCAP 64      // max samples tracked per class (Poisson(1): max ~10)
#define NCH 256         // 64-row K-chunks per matrix

typedef __attribute__((ext_vector_type(8))) short short8;  // 8 bf16 (4 VGPRs)
typedef __attribute__((ext_vector_type(4))) float f32x4;   // MFMA acc

__device__ __forceinline__ float wave_sum(float v) {
#pragma unroll
  for (int m = 32; m > 0; m >>= 1) v += __shfl_xor(v, m, 64);
  return v;
}

// --- 1. zero cnt + scal ---------------------------------------------------------
__global__ __launch_bounds__(256) void zero_kernel(int4* __restrict__ cnt4,
                                                   float* __restrict__ scal) {
  cnt4[blockIdx.x * 256 + threadIdx.x] = make_int4(0, 0, 0, 0);
  if (blockIdx.x == 0 && threadIdx.x < 16) scal[threadIdx.x] = 0.f;
}

// --- 2. scatter: slot[lab][k] = sample index --------------------------------------
__global__ __launch_bounds__(256) void scatter_kernel(
    const int* __restrict__ labels, int* __restrict__ cnt, int* __restrict__ slot) {
  int i = blockIdx.x * 256 + threadIdx.x;
  int lab = labels[i];
  int p = atomicAdd(&cnt[lab], 1);
  if (p < SLOTCAP) slot[(size_t)lab * SLOTCAP + p] = i;
}

// --- 3. centers + diag: one wave per class (R7/R13 verbatim) ----------------------
__global__ __launch_bounds__(256) void center_kernel(
    const float* __restrict__ z, const int* __restrict__ cnt,
    const int* __restrict__ slot, float* __restrict__ cn,
    float2* __restrict__ dpart) {
  __shared__ float red[8];
  int t = threadIdx.x, wave = t >> 6, lane = t & 63;
  int c = blockIdx.x * 4 + wave;

  int n = cnt[c];
  if (n > SLOTCAP) n = SLOTCAP;
  float2 s = make_float2(0.f, 0.f);
  for (int k = 0; k < n; ++k) {
    int i = slot[(size_t)c * SLOTCAP + k];
    float2 v = *(const float2*)&z[(size_t)i * FD + lane * 2];
    s.x += v.x; s.y += v.y;
  }
  float inv = n > 0 ? 1.0f / (float)n : 0.0f;
  s.x *= inv; s.y *= inv;
  float sc = wave_sum(s.x * s.x + s.y * s.y);
  float ic = 1.0f / fmaxf(sqrtf(sc), 1e-12f);
  s.x *= ic; s.y *= ic;
  *(float2*)&cn[(size_t)c * FD + lane * 2] = s;

  float2 a = *(const float2*)&z[(size_t)c * FD + lane * 2];
  float na = wave_sum(a.x * a.x + a.y * a.y);
  float dd = wave_sum(a.x * s.x + a.y * s.y);
  float d = dd * (1.0f / fmaxf(sqrtf(na), 1e-12f));
  if (lane == 0) { red[wave * 2] = d; red[wave * 2 + 1] = d * d; }
  __syncthreads();
  if (t == 0) {
    dpart[blockIdx.x] = make_float2(red[0] + red[2] + red[4] + red[6],
                                    red[1] + red[3] + red[5] + red[7]);
  }
}

// --- 4. gram partials via MFMA ----------------------------------------------------
// block b: matrix m=b&1 (0->z, 1->cn), 64-row chunk b>>1. G = T^T T (128x128).
// bf16 tile [64][130] (pad -> conflict-free column-slice frag reads);
// 4 waves x 16 tiles x 2 MFMA(16x16x32); G staged fp16 in LDS, coalesced out.
__global__ __launch_bounds__(256) void gram_kernel(
    const float* __restrict__ z, const float* __restrict__ cn,
    __half2* __restrict__ pz, __half2* __restrict__ pc) {
  __shared__ char lds[49920];
  unsigned short* B = (unsigned short*)lds;   // bf16 tile [64][130] = 16640 B
  float* U = (float*)(lds + 16640);           // fp32 stage [64][128] = 32768 B
                                              // (aliased later: G fp16 [128][130] = 33280 B)
  int t = threadIdx.x, wave = t >> 6, lane = t & 63;
  int b = blockIdx.x, m = b & 1, chunk = b >> 1;
  const float* A = m ? cn : z;

  {  // stage 64x128 fp32, coalesced float4
    const float4* src = (const float4*)&A[(size_t)chunk * 64 * FD];
    float4* dst = (float4*)U;
#pragma unroll
    for (int k = 0; k < 8; ++k) dst[k * 256 + t] = src[k * 256 + t];
  }
  __syncthreads();
  {  // normalize rows + convert to bf16 (cn rows already unit -> no-op renorm)
    const float2* t2 = (const float2*)U;
#pragma unroll
    for (int j = 0; j < 16; ++j) {
      int row = wave * 16 + j;
      float2 v = t2[row * 64 + lane];
      float ss = wave_sum(v.x * v.x + v.y * v.y);
      float sc = 1.0f / fmaxf(sqrtf(ss), 1e-12f);
      v.x *= sc; v.y *= sc;
      unsigned ux = __float_as_uint(v.x), uy = __float_as_uint(v.y);
      ux = (ux + 0x7FFFu + ((ux >> 16) & 1u)) >> 16;  // RNE f32->bf16
      uy = (uy + 0x7FFFu + ((uy >> 16) & 1u)) >> 16;
      *(unsigned*)&B[row * 130 + lane * 2] = ux | (uy << 16);
    }
  }
  __syncthreads();

  // fragment loads: frag[kb][cb] elem j = T[kb*32 + (lane>>4)*8 + j][cb*16 + (lane&15)]
  const unsigned short* Bl = B + (lane >> 4) * (8 * 130) + (lane & 15);
  short8 fr[2][8];
#pragma unroll
  for (int kb = 0; kb < 2; ++kb)
#pragma unroll
    for (int cb = 0; cb < 8; ++cb)
#pragma unroll
      for (int j = 0; j < 8; ++j)
        fr[kb][cb][j] = (short)Bl[kb * (32 * 130) + cb * 16 + j * 130];
  // dedicated A-frags for this wave's two tile-rows (avoid runtime reg indexing)
  short8 fa[2][2];
#pragma unroll
  for (int til = 0; til < 2; ++til) {
    const unsigned short* Al = Bl + (wave * 2 + til) * 16;
#pragma unroll
    for (int kb = 0; kb < 2; ++kb)
#pragma unroll
      for (int j = 0; j < 8; ++j)
        fa[til][kb][j] = (short)Al[kb * (32 * 130) + j * 130];
  }

  f32x4 acc[2][8];
#pragma unroll
  for (int i = 0; i < 2; ++i)
#pragma unroll
    for (int j = 0; j < 8; ++j)
      acc[i][j] = (f32x4){0.f, 0.f, 0.f, 0.f};

#pragma unroll
  for (int til = 0; til < 2; ++til)
#pragma unroll
    for (int tj = 0; tj < 8; ++tj) {
      acc[til][tj] = __builtin_amdgcn_mfma_f32_16x16x32_bf16(
          fa[til][0], fr[0][tj], acc[til][tj], 0, 0, 0);
      acc[til][tj] = __builtin_amdgcn_mfma_f32_16x16x32_bf16(
          fa[til][1], fr[1][tj], acc[til][tj], 0, 0, 0);
    }

  // write G to LDS fp16 [128][130] (aliases dead fp32 stage; != B region)
  unsigned short* G = (unsigned short*)(lds + 16640);
#pragma unroll
  for (int til = 0; til < 2; ++til)
#pragma unroll
    for (int tj = 0; tj < 8; ++tj)
#pragma unroll
      for (int q = 0; q < 4; ++q) {
        int d = (wave * 2 + til) * 16 + (lane >> 4) * 4 + q;  // C/D: row=(l>>4)*4+reg
        int e = tj * 16 + (lane & 15);                        //      col=l&15
        __half h = __float2half(acc[til][tj][q]);
        G[d * 130 + e] = *(unsigned short*)&h;
      }
  __syncthreads();

  // coalesced copy-out: [128][64 half2] row-major (same layout reduce expects)
  unsigned* Pg = (unsigned*)((m ? pc : pz) + (size_t)chunk * 8192);
#pragma unroll
  for (int it = 0; it < 32; ++it) {
    int row = it * 4 + (t >> 6);
    int h2i = t & 63;
    Pg[row * 64 + h2i] = *(const unsigned*)(lds + 16640 + row * 260 + h2i * 4);
  }
}

// --- 5. reduce fp16 partials + Frobenius + loss (R13 verbatim) --------------------
__global__ __launch_bounds__(256) void reduce_final_kernel(
    const __half2* __restrict__ pz, const __half2* __restrict__ pc,
    const float2* __restrict__ dpart, float* __restrict__ scal,
    int* __restrict__ ticket_p, float* __restrict__ out) {
  __shared__ float2 lz[4][64], lc[4][64];
  __shared__ float rr[2][4];
  __shared__ int tk;
  int t = threadIdx.x, wave = t >> 6, lane = t & 63;
  int e2 = blockIdx.x * 64 + lane;
  float2 sz = make_float2(0.f, 0.f), sc = make_float2(0.f, 0.f);
  for (int k = 0; k < NCH / 4; ++k) {
    size_t c = (size_t)(wave * (NCH / 4) + k) * 8192 + e2;
    float2 fz = __half22float2(pz[c]);
    float2 fc = __half22float2(pc[c]);
    sz.x += fz.x; sz.y += fz.y;
    sc.x += fc.x; sc.y += fc.y;
  }
  lz[wave][lane] = sz;
  lc[wave][lane] = sc;
  __syncthreads();
  if (wave == 0) {
    float2 tz = make_float2(0.f, 0.f), tc = make_float2(0.f, 0.f);
#pragma unroll
    for (int w = 0; w < 4; ++w) {
      tz.x += lz[w][lane].x; tz.y += lz[w][lane].y;
      tc.x += lc[w][lane].x; tc.y += lc[w][lane].y;
    }
    float S = wave_sum(tz.x * tc.x + tz.y * tc.y);
    if (lane == 0) {
      unsafeAtomicAdd(&scal[2], S);
      __threadfence();
      tk = atomicAdd(ticket_p, 1);
    }
  }
  __syncthreads();
  if (tk == 127) {  // last block: compose loss with all 256 threads coalesced
    float a1 = 0.f, a2 = 0.f;
#pragma unroll
    for (int k = 0; k < 16; ++k) {
      float2 d = dpart[k * 256 + t];
      a1 += d.x; a2 += d.y;
    }
    a1 = wave_sum(a1);
    a2 = wave_sum(a2);
    if (lane == 0) { rr[0][wave] = a1; rr[1][wave] = a2; }
    __syncthreads();
    if (t == 0) {
      float SS = atomicAdd(&scal[2], 0.0f);
      double S1 = (double)rr[0][0] + rr[0][1] + rr[0][2] + rr[0][3];
      double S2 = (double)rr[1][0] + rr[1][1] + rr[1][2] + rr[1][3];
      double Sall = SS;
      double B = (double)NC;
      double inv_loss = S2 / (B * B) - 2.0 * S1 / B + (double)NC;
      double red_loss = (Sall - S2) / (B * B);
      out[0] = (float)(inv_loss + (double)LAMBDA * red_loss);
    }
  }
}

extern "C" void kernel_launch(void* const* d_in, const int* in_sizes, int n_in,
                              void* d_out, int out_size, void* d_ws, size_t ws_size,
                              hipStream_t stream) {
  const float* z = (const float*)d_in[0];
  const int* labels = (const int*)d_in[1];
  float* out = (float*)d_out;
  float* ws = (float*)d_ws;

  // ws layout (floats):
  // [cn NC*FD][pz NCH*8192 h2][pc NCH*8192 h2][dpart 4096 f2][scal 16]
  // [cnt NC int][slot NC*SLOTCAP int]
  float* cn = ws;
  __half2* pz = (__half2*)(cn + (size_t)NC * FD);
  __half2* pc = pz + (size_t)NCH * 8192;
  float2* dpart = (float2*)(pc + (size_t)NCH * 8192);
  float* scal = (float*)(dpart + 4096);
  int* cnt = (int*)(scal + 16);
  int* slot = cnt + NC;
  int* ticket = (int*)&scal[8];

  zero_kernel<<<NC / 1024, 256, 0, stream>>>((int4*)cnt, scal);
  scatter_kernel<<<NC / 256, 256, 0, stream>>>(labels, cnt, slot);
  center_kernel<<<NC / 4, 256, 0, stream>>>(z, cnt, slot, cn, dpart);
  gram_kernel<<<2 * NCH, 256, 0, stream>>>(z, cn, pz, pc);
  reduce_final_kernel<<<128, 256, 0, stream>>>(pz, pc, dpart, scal, ticket, out);
}

// Round 15
// 37.743 us; speedup vs baseline: 7.8477x; 1.2357x over previous
//
#include <hip/hip_runtime.h>
#include <hip/hip_fp16.h>

#define NC 16384        // num classes == batch
#define FD 128          // feature dim
#define LAMBDA 0.005f
#define SLOTCAP 64      // max samples tracked per class (Poisson(1): max ~10)
#define NPAIR 128       // 128-row pairs (2x64 chunks) per matrix

typedef __attribute__((ext_vector_type(8))) short short8;  // 8 bf16 (4 VGPRs)
typedef __attribute__((ext_vector_type(4))) float f32x4;   // MFMA acc

__device__ __forceinline__ float wave_sum(float v) {
#pragma unroll
  for (int m = 32; m > 0; m >>= 1) v += __shfl_xor(v, m, 64);
  return v;
}

__device__ __forceinline__ unsigned pack_bf16(float x, float y) {
  unsigned ux = __float_as_uint(x), uy = __float_as_uint(y);
  ux = (ux + 0x7FFFu + ((ux >> 16) & 1u)) >> 16;  // RNE f32->bf16
  uy = (uy + 0x7FFFu + ((uy >> 16) & 1u)) >> 16;
  return ux | (uy << 16);
}

// --- 1. zero cnt + scal ---------------------------------------------------------
__global__ __launch_bounds__(256) void zero_kernel(int4* __restrict__ cnt4,
                                                   float* __restrict__ scal) {
  cnt4[blockIdx.x * 256 + threadIdx.x] = make_int4(0, 0, 0, 0);
  if (blockIdx.x == 0 && threadIdx.x < 16) scal[threadIdx.x] = 0.f;
}

// --- 2. scatter: slot[lab][k] = sample index --------------------------------------
__global__ __launch_bounds__(256) void scatter_kernel(
    const int* __restrict__ labels, int* __restrict__ cnt, int* __restrict__ slot) {
  int i = blockIdx.x * 256 + threadIdx.x;
  int lab = labels[i];
  int p = atomicAdd(&cnt[lab], 1);
  if (p < SLOTCAP) slot[(size_t)lab * SLOTCAP + p] = i;
}

// --- 3. centers + diag -> bf16 zn/cn; parallel-issued load chain -------------------
__global__ __launch_bounds__(256) void center_kernel(
    const float* __restrict__ z, const int* __restrict__ cnt,
    const int* __restrict__ slot, unsigned* __restrict__ cnb,
    unsigned* __restrict__ znb, float2* __restrict__ dpart) {
  __shared__ float red[8];
  int t = threadIdx.x, wave = t >> 6, lane = t & 63;
  int c = blockIdx.x * 4 + wave;

  // independent loads issued together: slot int4, cnt, diag z row
  int4 s4 = *(const int4*)&slot[(size_t)c * SLOTCAP];
  int n = cnt[c];
  float2 a = *(const float2*)&z[(size_t)c * FD + lane * 2];
  if (n > SLOTCAP) n = SLOTCAP;

  // up to 4 gathered rows in parallel (predicated index; safe dummy = row c)
  int i0 = n > 0 ? s4.x : c, i1 = n > 1 ? s4.y : c;
  int i2 = n > 2 ? s4.z : c, i3 = n > 3 ? s4.w : c;
  float2 v0 = *(const float2*)&z[(size_t)i0 * FD + lane * 2];
  float2 v1 = *(const float2*)&z[(size_t)i1 * FD + lane * 2];
  float2 v2 = *(const float2*)&z[(size_t)i2 * FD + lane * 2];
  float2 v3 = *(const float2*)&z[(size_t)i3 * FD + lane * 2];
  float2 s = make_float2(0.f, 0.f);
  if (n > 0) { s.x += v0.x; s.y += v0.y; }
  if (n > 1) { s.x += v1.x; s.y += v1.y; }
  if (n > 2) { s.x += v2.x; s.y += v2.y; }
  if (n > 3) { s.x += v3.x; s.y += v3.y; }
  for (int k = 4; k < n; ++k) {  // rare (Poisson(1) tail)
    int i = slot[(size_t)c * SLOTCAP + k];
    float2 v = *(const float2*)&z[(size_t)i * FD + lane * 2];
    s.x += v.x; s.y += v.y;
  }
  float inv = n > 0 ? 1.0f / (float)n : 0.0f;
  s.x *= inv; s.y *= inv;
  float sc = wave_sum(s.x * s.x + s.y * s.y);
  float ic = 1.0f / fmaxf(sqrtf(sc), 1e-12f);
  s.x *= ic; s.y *= ic;
  cnb[(size_t)c * 64 + lane] = pack_bf16(s.x, s.y);

  // diag + normalized z row out
  float na = wave_sum(a.x * a.x + a.y * a.y);
  float ia = 1.0f / fmaxf(sqrtf(na), 1e-12f);
  float dd = wave_sum(a.x * s.x + a.y * s.y);
  float d = dd * ia;
  znb[(size_t)c * 64 + lane] = pack_bf16(a.x * ia, a.y * ia);

  if (lane == 0) { red[wave * 2] = d; red[wave * 2 + 1] = d * d; }
  __syncthreads();
  if (t == 0) {
    dpart[blockIdx.x] = make_float2(red[0] + red[2] + red[4] + red[6],
                                    red[1] + red[3] + red[5] + red[7]);
  }
}

// --- 4. gram partials via MFMA: 2 chunks (128 rows) accumulated per block ----------
// block b: matrix m=b&1 (0->znb, 1->cnb), pair=b>>1. G = T^T T over rows
// [pair*128, pair*128+128). bf16 tiles B0/B1 [64][130]; G fp16 [128][130] aliases.
__global__ __launch_bounds__(256) void gram_kernel(
    const unsigned short* __restrict__ znb, const unsigned short* __restrict__ cnb,
    __half2* __restrict__ pz, __half2* __restrict__ pc) {
  __shared__ char lds[33280];
  unsigned short* Bu = (unsigned short*)lds;  // B0 @0, B1 @8320 (u16 units)
  int t = threadIdx.x, wave = t >> 6, lane = t & 63;
  int b = blockIdx.x, m = b & 1, pair = b >> 1;
  const unsigned short* Ab = m ? cnb : znb;

  {  // stage both 64x128 bf16 chunks, coalesced int4 (32 KB total)
    const int4* src = (const int4*)(Ab + (size_t)pair * 16384);
#pragma unroll
    for (int k = 0; k < 8; ++k) {
      int idx = k * 256 + t;
      int q = idx >> 10, idx2 = idx & 1023;
      int row = idx2 >> 4, col8 = idx2 & 15;
      *(int4*)&Bu[q * 8320 + row * 130 + col8 * 8] = src[idx];
    }
  }
  __syncthreads();

  f32x4 acc[2][8];
#pragma unroll
  for (int i = 0; i < 2; ++i)
#pragma unroll
    for (int j = 0; j < 8; ++j)
      acc[i][j] = (f32x4){0.f, 0.f, 0.f, 0.f};

#pragma unroll
  for (int q = 0; q < 2; ++q) {
    const unsigned short* Bl = Bu + q * 8320 + (lane >> 4) * (8 * 130) + (lane & 15);
    short8 fr[2][8];
#pragma unroll
    for (int kb = 0; kb < 2; ++kb)
#pragma unroll
      for (int cb = 0; cb < 8; ++cb)
#pragma unroll
        for (int j = 0; j < 8; ++j)
          fr[kb][cb][j] = (short)Bl[kb * 4160 + cb * 16 + j * 130];
    short8 fa[2][2];
#pragma unroll
    for (int til = 0; til < 2; ++til)
#pragma unroll
      for (int kb = 0; kb < 2; ++kb)
#pragma unroll
        for (int j = 0; j < 8; ++j)
          fa[til][kb][j] = (short)Bl[kb * 4160 + (wave * 2 + til) * 16 + j * 130];
#pragma unroll
    for (int til = 0; til < 2; ++til)
#pragma unroll
      for (int tj = 0; tj < 8; ++tj) {
        acc[til][tj] = __builtin_amdgcn_mfma_f32_16x16x32_bf16(
            fa[til][0], fr[0][tj], acc[til][tj], 0, 0, 0);
        acc[til][tj] = __builtin_amdgcn_mfma_f32_16x16x32_bf16(
            fa[til][1], fr[1][tj], acc[til][tj], 0, 0, 0);
      }
  }
  __syncthreads();  // all frag reads done; safe to alias G over B0/B1

  unsigned short* G = (unsigned short*)lds;  // fp16 [128][130]
#pragma unroll
  for (int til = 0; til < 2; ++til)
#pragma unroll
    for (int tj = 0; tj < 8; ++tj)
#pragma unroll
      for (int q = 0; q < 4; ++q) {
        int d = (wave * 2 + til) * 16 + (lane >> 4) * 4 + q;  // C/D: row=(l>>4)*4+reg
        int e = tj * 16 + (lane & 15);                        //      col=l&15
        __half h = __float2half(acc[til][tj][q]);
        G[d * 130 + e] = *(unsigned short*)&h;
      }
  __syncthreads();

  // coalesced copy-out: [128][64 half2] row-major
  unsigned* Pg = (unsigned*)((m ? pc : pz) + (size_t)pair * 8192);
#pragma unroll
  for (int it = 0; it < 32; ++it) {
    int row = it * 4 + (t >> 6);
    int h2i = t & 63;
    Pg[row * 64 + h2i] = *(const unsigned*)(lds + row * 260 + h2i * 4);
  }
}

// --- 5. reduce fp16 partials + Frobenius + loss (ticket; full-block last sum) ------
__global__ __launch_bounds__(256) void reduce_final_kernel(
    const __half2* __restrict__ pz, const __half2* __restrict__ pc,
    const float2* __restrict__ dpart, float* __restrict__ scal,
    int* __restrict__ ticket_p, float* __restrict__ out) {
  __shared__ float2 lz[4][64], lc[4][64];
  __shared__ float rr[2][4];
  __shared__ int tk;
  int t = threadIdx.x, wave = t >> 6, lane = t & 63;
  int e2 = blockIdx.x * 64 + lane;  // half2 index in [0, 8192)
  float2 sz = make_float2(0.f, 0.f), sc = make_float2(0.f, 0.f);
  for (int k = 0; k < NPAIR / 4; ++k) {
    size_t c = (size_t)(wave * (NPAIR / 4) + k) * 8192 + e2;
    float2 fz = __half22float2(pz[c]);
    float2 fc = __half22float2(pc[c]);
    sz.x += fz.x; sz.y += fz.y;
    sc.x += fc.x; sc.y += fc.y;
  }
  lz[wave][lane] = sz;
  lc[wave][lane] = sc;
  __syncthreads();
  if (wave == 0) {
    float2 tz = make_float2(0.f, 0.f), tc = make_float2(0.f, 0.f);
#pragma unroll
    for (int w = 0; w < 4; ++w) {
      tz.x += lz[w][lane].x; tz.y += lz[w][lane].y;
      tc.x += lc[w][lane].x; tc.y += lc[w][lane].y;
    }
    float S = wave_sum(tz.x * tc.x + tz.y * tc.y);
    if (lane == 0) {
      unsafeAtomicAdd(&scal[2], S);
      __threadfence();
      tk = atomicAdd(ticket_p, 1);
    }
  }
  __syncthreads();
  if (tk == 127) {  // last block: compose loss with all 256 threads coalesced
    float a1 = 0.f, a2 = 0.f;
#pragma unroll
    for (int k = 0; k < 16; ++k) {
      float2 d = dpart[k * 256 + t];
      a1 += d.x; a2 += d.y;
    }
    a1 = wave_sum(a1);
    a2 = wave_sum(a2);
    if (lane == 0) { rr[0][wave] = a1; rr[1][wave] = a2; }
    __syncthreads();
    if (t == 0) {
      float SS = atomicAdd(&scal[2], 0.0f);
      double S1 = (double)rr[0][0] + rr[0][1] + rr[0][2] + rr[0][3];
      double S2 = (double)rr[1][0] + rr[1][1] + rr[1][2] + rr[1][3];
      double Sall = SS;
      double B = (double)NC;
      double inv_loss = S2 / (B * B) - 2.0 * S1 / B + (double)NC;
      double red_loss = (Sall - S2) / (B * B);
      out[0] = (float)(inv_loss + (double)LAMBDA * red_loss);
    }
  }
}

extern "C" void kernel_launch(void* const* d_in, const int* in_sizes, int n_in,
                              void* d_out, int out_size, void* d_ws, size_t ws_size,
                              hipStream_t stream) {
  const float* z = (const float*)d_in[0];
  const int* labels = (const int*)d_in[1];
  float* out = (float*)d_out;
  float* ws = (float*)d_ws;

  // ws layout (u32 units):
  // [pz NPAIR*8192 h2][pc NPAIR*8192 h2][znb NC*64 u32][cnb NC*64 u32]
  // [dpart 4096 f2][scal 16 f][cnt NC int][slot NC*SLOTCAP int]
  __half2* pz = (__half2*)ws;
  __half2* pc = pz + (size_t)NPAIR * 8192;
  unsigned* znb = (unsigned*)(pc + (size_t)NPAIR * 8192);
  unsigned* cnb = znb + (size_t)NC * 64;
  float2* dpart = (float2*)(cnb + (size_t)NC * 64);
  float* scal = (float*)(dpart + 4096);
  int* cnt = (int*)(scal + 16);
  int* slot = cnt + NC;
  int* ticket = (int*)&scal[8];

  zero_kernel<<<NC / 1024, 256, 0, stream>>>((int4*)cnt, scal);
  scatter_kernel<<<NC / 256, 256, 0, stream>>>(labels, cnt, slot);
  center_kernel<<<NC / 4, 256, 0, stream>>>(z, cnt, slot, cnb, znb, dpart);
  gram_kernel<<<2 * NPAIR, 256, 0, stream>>>((const unsigned short*)znb,
                                             (const unsigned short*)cnb, pz, pc);
  reduce_final_kernel<<<128, 256, 0, stream>>>(pz, pc, dpart, scal, ticket, out);
}